// Round 20
// baseline (129.473 us; speedup 1.0000x reference)
//
#include <hip/hip_runtime.h>
#include <hip/hip_bf16.h>
#include <stdint.h>

typedef unsigned short u16;
typedef unsigned int   u32;
typedef __attribute__((ext_vector_type(4))) float f32x4;
typedef __attribute__((ext_vector_type(8))) short bf16x8;

__device__ __forceinline__ u16 f2bf(float x){
  u32 u = __float_as_uint(x);
  return (u16)((u + 0x7fffu + ((u >> 16) & 1u)) >> 16);   // RNE
}

__device__ __forceinline__ u32 pkbf(float a, float b){
  __hip_bfloat162 t = __float22bfloat162_rn(make_float2(a, b));  // v_cvt_pk_bf16_f32
  u32 r; __builtin_memcpy(&r, &t, 4); return r;
}

// raw v_exp_f32 (2^x): args always in [-50,-17] -> OCML range-fixup is dead code.
__device__ __forceinline__ float fexp2(float x){
  float r; asm("v_exp_f32 %0, %1" : "=v"(r) : "v"(x)); return r;
}

// v_permlane16_swap_b32 (Sem A, HW-confirmed R6/R7): d.row1<->s.row0, d.row3<->s.row2.
__device__ __forceinline__ void pl16swap(u32 &d, u32 &s){
  asm("v_permlane16_swap_b32 %0, %1" : "+v"(d), "+v"(s));
}

__device__ __forceinline__ bf16x8 mk8(u32 a, u32 b, u32 c, u32 d){
  union { u32 w[4]; bf16x8 v; } t; t.w[0]=a; t.w[1]=b; t.w[2]=c; t.w[3]=d; return t.v;
}

__device__ __forceinline__ void async_cp16(const void* g, void* l){
  __builtin_amdgcn_global_load_lds((const __attribute__((address_space(1))) void*)g,
                                   (__attribute__((address_space(3))) void*)l, 16, 0, 0);
}

// ---------------------------------------------------------------- converts: WEIGHTS ONLY
__device__ __forceinline__ void conv_body(const float* __restrict__ x,
                                          u16* __restrict__ hi, int i){
  float4 v = *(const float4*)(x + i);
  ushort4 hv; hv.x = f2bf(v.x); hv.y = f2bf(v.y); hv.z = f2bf(v.z); hv.w = f2bf(v.w);
  *(ushort4*)(hi + i) = hv;
}

__global__ __launch_bounds__(256) void conv_all(
    const float* __restrict__ w1, const float* __restrict__ w2,
    const float* __restrict__ w3, const float* __restrict__ w4,
    u16* w1h, u16* w2h, u16* w3h, u16* w4h)
{
  const int o = blockIdx.x;
  const int z = o >> 10;
  const int blk = o & 1023;
  const float* x = (z == 0) ? w1 : (z == 1) ? w2 : (z == 2) ? w3 : w4;
  u16* y = (z == 0) ? w1h : (z == 1) ? w2h : (z == 2) ? w3h : w4h;
  conv_body(x, y, (blk * 256 + threadIdx.x) * 4);
}

// ---------------------------------------------------------------- fused proj v3: ONE barrier/iter
// lA[2]+lB[2] = 64KB. Iter t: issue A(t+1)-regs + B(t+1)-gload FIRST (latency hides under
// compute), compute(t) from buffers cur, then vmcnt(4) [A regs only; B stays in flight],
// cvt+write lA[cur^1], vmcnt(0)+lgkmcnt(0), ONE s_barrier. Buffer cur^1's readers drained
// at the previous barrier -> race-free. Values + MFMA order unchanged -> bitwise-identical.
__global__ __launch_bounds__(256, 2) void proj_kernel(
    const float* __restrict__ qf, const float* __restrict__ kf, const float* __restrict__ vf,
    const u16* __restrict__ w1h, const u16* __restrict__ w2h, const u16* __restrict__ w3h,
    const float* b1, const float* b2, const float* b3,
    u16* Qb, u16* Kb, u16* VbT)
{
  __shared__ u16 lA[2][8192];
  __shared__ u16 lB[2][8192];

  const int o = blockIdx.x;
  const int swz = (o & 7) * 96 + (o >> 3);
  const int x = swz & 7, y = (swz >> 3) & 31, z = swz >> 8;
  const float* Af; const u16* Bw; const float* bs; float sc;
  if (z == 0){ Af = qf; Bw = w1h; bs = b1; sc = 0.18033688011112042f; }   // 1/sqrt(dk) * log2e
  else if (z == 1){ Af = kf; Bw = w2h; bs = b2; sc = 1.0f; }
  else { Af = vf; Bw = w3h; bs = b3; sc = 1.0f; }

  const int tid  = threadIdx.x;
  const int lane = tid & 63, wid = tid >> 6;
  const int li = lane & 15, g = lane >> 4;
  const int wr = wid >> 1, wc = wid & 1;
  const int m0 = y * 128, n0 = x * 128;

  const int r0 = tid >> 3, c0 = tid & 7;
  const size_t gsB = (size_t)r0 * 1024 + (size_t)((c0 ^ (r0 & 7)) * 8);
  const u16* pB = Bw + (size_t)n0 * 1024;

  const int ar0 = wid * 32 + (lane >> 3);
  const int ac  = lane & 7;
  const int awb = ((ac ^ (lane >> 3)) << 4);
  const float* pA = Af + (size_t)m0 * 1024;

  float4 ap[4][2];
  auto loadA = [&](int k0){
    #pragma unroll
    for (int p = 0; p < 4; p++){
      const float* s = pA + (size_t)(ar0 + 8 * p) * 1024 + k0 + ac * 8;
      ap[p][0] = *(const float4*)s;
      ap[p][1] = *(const float4*)(s + 4);
    }
  };
  auto writeA = [&](int buf){
    #pragma unroll
    for (int p = 0; p < 4; p++){
      uint4 wv;
      wv.x = pkbf(ap[p][0].x, ap[p][0].y);
      wv.y = pkbf(ap[p][0].z, ap[p][0].w);
      wv.z = pkbf(ap[p][1].x, ap[p][1].y);
      wv.w = pkbf(ap[p][1].z, ap[p][1].w);
      *(uint4*)((char*)lA + buf * 16384 + (ar0 + 8 * p) * 128 + awb) = wv;
    }
  };
  auto stageB = [&](int k0, int buf){
    #pragma unroll
    for (int s = 0; s < 4; s++)
      async_cp16(pB + gsB + k0 + (size_t)s * 32 * 1024,
                 (char*)lB + buf * 16384 + wid * 1024 + s * 4096);
  };

  f32x4 acc[4][4];
  #pragma unroll
  for (int i = 0; i < 4; i++)
    #pragma unroll
    for (int j = 0; j < 4; j++) acc[i][j] = (f32x4){0.f, 0.f, 0.f, 0.f};

  // prologue: A(0) + B(0) into buffer 0
  loadA(0);
  __builtin_amdgcn_sched_barrier(0);          // pin: A vmem before B gload (vmcnt(4) isolates A)
  stageB(0, 0);
  asm volatile("s_waitcnt vmcnt(4)" ::: "memory");
  __builtin_amdgcn_sched_barrier(0);
  writeA(0);
  asm volatile("s_waitcnt vmcnt(0) lgkmcnt(0)" ::: "memory");
  __builtin_amdgcn_sched_barrier(0);
  __builtin_amdgcn_s_barrier();

  int cur = 0;
  for (int t = 0; t < 16; t++){
    if (t < 15){
      loadA((t + 1) * 64);
      __builtin_amdgcn_sched_barrier(0);      // A before B
      stageB((t + 1) * 64, cur ^ 1);
    }

    const char* Ab = (const char*)lA + cur * 16384;
    const char* Bb = (const char*)lB + cur * 16384;
    #pragma unroll
    for (int kk = 0; kk < 2; kk++){
      bf16x8 af[4], bf4[4];
      #pragma unroll
      for (int f = 0; f < 4; f++){
        int ar = wr * 64 + f * 16 + li;
        int ja = (kk * 4 + g) ^ (ar & 7);
        af[f] = *(const bf16x8*)(Ab + ar * 128 + (ja << 4));
        int br = wc * 64 + f * 16 + li;
        int jb = (kk * 4 + g) ^ (br & 7);
        bf4[f] = *(const bf16x8*)(Bb + br * 128 + (jb << 4));
      }
      __builtin_amdgcn_s_setprio(1);
      #pragma unroll
      for (int fm = 0; fm < 4; fm++)
        #pragma unroll
        for (int fn = 0; fn < 4; fn++)
          acc[fm][fn] = __builtin_amdgcn_mfma_f32_16x16x32_bf16(af[fm], bf4[fn], acc[fm][fn], 0, 0, 0);
      __builtin_amdgcn_s_setprio(0);
    }

    if (t < 15){
      asm volatile("s_waitcnt vmcnt(4)" ::: "memory");   // A(t+1) regs landed; B stays in flight
      __builtin_amdgcn_sched_barrier(0);
      writeA(cur ^ 1);
    }
    asm volatile("s_waitcnt vmcnt(0) lgkmcnt(0)" ::: "memory");  // B(t+1) landed + writes done
    __builtin_amdgcn_sched_barrier(0);
    __builtin_amdgcn_s_barrier();
    cur ^= 1;
  }

  float bv[4];
  #pragma unroll
  for (int fn = 0; fn < 4; fn++) bv[fn] = bs[n0 + wc * 64 + fn * 16 + li];

  if (z != 2){
    u16* out = (z == 0) ? Qb : Kb;
    #pragma unroll
    for (int fm = 0; fm < 4; fm++){
      const int mb = m0 + wr * 64 + fm * 16 + g * 4;
      #pragma unroll
      for (int fn = 0; fn < 4; fn++){
        const int n = n0 + wc * 64 + fn * 16 + li;
        #pragma unroll
        for (int r = 0; r < 4; r++)
          out[(size_t)(mb + r) * 1024 + n] = f2bf((acc[fm][fn][r] + bv[fn]) * sc);
      }
    }
  } else {
    // transposed: VbT[((b*16+h)*64+d)*2048 + seq], seq = (m0&2047)+wr*64+fm*16+g*4+r
    const int bb = m0 >> 11;
    const int sq0 = (m0 & 2047) + wr * 64 + g * 4;
    #pragma unroll
    for (int fm = 0; fm < 4; fm++){
      #pragma unroll
      for (int fn = 0; fn < 4; fn++){
        const int n = n0 + wc * 64 + fn * 16 + li;
        const int hh = n >> 6, dd = n & 63;
        ushort4 hv;
        #pragma unroll
        for (int r = 0; r < 4; r++)
          ((u16*)&hv)[r] = f2bf(acc[fm][fn][r] + bv[fn]);
        size_t idx = ((size_t)(bb * 16 + hh) * 64 + dd) * 2048 + sq0 + fm * 16;
        *(ushort4*)(VbT + idx) = hv;
      }
    }
  }
}

// ---------------------------------------------------------------- fin: 128x64 tile, 512 blocks (2/CU)
__global__ __launch_bounds__(256, 2) void fin_kernel(
    const u16* __restrict__ A, const u16* __restrict__ B,
    const float* __restrict__ bias, float* __restrict__ out)
{
  __shared__ u16 lA[8192], lB[4096];   // A 128x64 (16KB), B 64x64 (8KB)
  const int tid  = threadIdx.x;
  const int lane = tid & 63, wid = tid >> 6;
  const int li = lane & 15, g = lane >> 4;
  const int wr = wid >> 1, wc = wid & 1;

  const int o = blockIdx.x;
  const int swz = (o & 7) * 64 + (o >> 3);
  const int x = swz & 15, y = swz >> 4;
  const int m0 = y * 128, n0 = x * 64;

  const u16* pA = A + (size_t)m0 * 1024;
  const u16* pB = B + (size_t)n0 * 1024;

  const int r0 = tid >> 3, c0 = tid & 7;
  const size_t gsrc = (size_t)r0 * 1024 + (size_t)((c0 ^ (r0 & 7)) * 8);
  char* dA = (char*)lA + wid * 1024;
  char* dB = (char*)lB + wid * 1024;

  f32x4 acc[4][2];
  #pragma unroll
  for (int i = 0; i < 4; i++)
    #pragma unroll
    for (int j = 0; j < 2; j++) acc[i][j] = (f32x4){0.f, 0.f, 0.f, 0.f};

  for (int k0 = 0; k0 < 1024; k0 += 64){
    __syncthreads();
    #pragma unroll
    for (int s = 0; s < 4; s++)
      async_cp16(pA + gsrc + k0 + (size_t)s * 32 * 1024, dA + s * 4096);
    #pragma unroll
    for (int s = 0; s < 2; s++)
      async_cp16(pB + gsrc + k0 + (size_t)s * 32 * 1024, dB + s * 4096);
    __syncthreads();

    #pragma unroll
    for (int kk = 0; kk < 2; kk++){
      bf16x8 af[4], bf2[2];
      #pragma unroll
      for (int f = 0; f < 4; f++){
        int ar = wr * 64 + f * 16 + li;
        int ja = (kk * 4 + g) ^ (ar & 7);
        af[f] = *(const bf16x8*)((const char*)lA + ar * 128 + (ja << 4));
      }
      #pragma unroll
      for (int f = 0; f < 2; f++){
        int br = wc * 32 + f * 16 + li;
        int jb = (kk * 4 + g) ^ (br & 7);
        bf2[f] = *(const bf16x8*)((const char*)lB + br * 128 + (jb << 4));
      }
      __builtin_amdgcn_s_setprio(1);
      #pragma unroll
      for (int fm = 0; fm < 4; fm++)
        #pragma unroll
        for (int fn = 0; fn < 2; fn++)
          acc[fm][fn] = __builtin_amdgcn_mfma_f32_16x16x32_bf16(af[fm], bf2[fn], acc[fm][fn], 0, 0, 0);
      __builtin_amdgcn_s_setprio(0);
    }
  }

  float bv[2];
  #pragma unroll
  for (int fn = 0; fn < 2; fn++) bv[fn] = bias[n0 + wc * 32 + fn * 16 + li];

  #pragma unroll
  for (int fm = 0; fm < 4; fm++){
    const int mb = m0 + wr * 64 + fm * 16 + g * 4;
    #pragma unroll
    for (int fn = 0; fn < 2; fn++){
      const int n = n0 + wc * 32 + fn * 16 + li;
      #pragma unroll
      for (int r = 0; r < 4; r++)
        out[(size_t)(mb + r) * 1024 + n] = acc[fm][fn][r] + bv[fn];
    }
  }
}

// ---------------------------------------------------------------- flash attention v13 (frozen)
__global__ __launch_bounds__(256) void attn_kernel(
    const u16* __restrict__ Qb, const u16* __restrict__ Kb, const u16* __restrict__ VbT,
    u16* __restrict__ AOh)
{
  __shared__ char SL[3][16384];   // per buf: K [64k][64d] 8KB, V [64d][64k] 8KB

  const int tid = threadIdx.x;
  const int lane = tid & 63, wid = tid >> 6;
  const int li = lane & 15, g = lane >> 4;

  const int o = blockIdx.x;
  const int swz = (o & 7) * 64 + (o >> 3);
  const int qt = swz & 15, h = (swz >> 4) & 15, b = swz >> 8;

  const int r0 = tid >> 3, ch = tid & 7;
  const int csw = (ch ^ (r0 & 7)) * 8;
  const u16* gK = Kb  + (size_t)(b * 2048 + r0) * 1024 + h * 64 + csw;
  const u16* gV = VbT + ((size_t)(b * 16 + h) * 64 + r0) * 2048 + csw;
  const int ldsW = wid * 1024;

  const int kb0 = li * 128 + ((g ^ (li & 7)) << 4);
  const int cm = ((((g & 1) << 1) | ((g >> 1) & 1)) ^ 2);
  const int vp0 = ((cm ^ (li & 7)) << 4);
  const int vp1 = (((4 + cm) ^ (li & 7)) << 4);

  const u16* qp = Qb + (size_t)(b * 2048 + qt * 128 + wid * 32 + li) * 1024 + h * 64 + g * 8;
  bf16x8 qf[2][2];
  qf[0][0] = *(const bf16x8*)(qp);
  qf[0][1] = *(const bf16x8*)(qp + 32);
  qf[1][0] = *(const bf16x8*)(qp + 16 * 1024);
  qf[1][1] = *(const bf16x8*)(qp + 16 * 1024 + 32);

  f32x4 O[2][4];
  #pragma unroll
  for (int st = 0; st < 2; st++)
    #pragma unroll
    for (int df = 0; df < 4; df++) O[st][df] = (f32x4){0.f, 0.f, 0.f, 0.f};
  f32x4 Lacc[2];
  Lacc[0] = (f32x4){0.f, 0.f, 0.f, 0.f};
  Lacc[1] = (f32x4){0.f, 0.f, 0.f, 0.f};
  const f32x4 NEGC = (f32x4){-32.f, -32.f, -32.f, -32.f};
  const u32 one2 = 0x3f803f80u;
  const bf16x8 ones = mk8(one2, one2, one2, one2);

  auto stage = [&](int t, char* buf){
    #pragma unroll
    for (int c = 0; c < 2; c++){
      async_cp16(gK + (size_t)(t * 64 + c * 32) * 1024, buf + c * 4096 + ldsW);
      async_cp16(gV + (size_t)c * 32 * 2048 + t * 64,   buf + 8192 + c * 4096 + ldsW);
    }
  };

  auto qkt = [&](const char* buf, f32x4 sc[2][4]){
    __builtin_amdgcn_s_setprio(1);
    #pragma unroll
    for (int fn = 0; fn < 4; fn++){
      bf16x8 kf0 = *(const bf16x8*)(buf + fn * 2048 + kb0);
      bf16x8 kf1 = *(const bf16x8*)(buf + fn * 2048 + (kb0 ^ 64));
      #pragma unroll
      for (int st = 0; st < 2; st++){
        f32x4 z = __builtin_amdgcn_mfma_f32_16x16x32_bf16(kf0, qf[st][0], NEGC, 0, 0, 0);
        sc[st][fn] = __builtin_amdgcn_mfma_f32_16x16x32_bf16(kf1, qf[st][1], z, 0, 0, 0);
      }
    }
    __builtin_amdgcn_s_setprio(0);
  };

  auto sfpv = [&](const f32x4 sc[2][4], const char* vbuf){
    bf16x8 pa[2][2];
    #pragma unroll
    for (int st = 0; st < 2; st++){
      float p[4][4];
      #pragma unroll
      for (int fn = 0; fn < 4; fn++)
        #pragma unroll
        for (int r = 0; r < 4; r++)
          p[fn][r] = fexp2(sc[st][fn][r]);
      #pragma unroll
      for (int ks = 0; ks < 2; ks++){
        u32 a0 = pkbf(p[2 * ks][0],     p[2 * ks][1]);
        u32 a1 = pkbf(p[2 * ks][2],     p[2 * ks][3]);
        u32 b0 = pkbf(p[2 * ks + 1][0], p[2 * ks + 1][1]);
        u32 b1 = pkbf(p[2 * ks + 1][2], p[2 * ks + 1][3]);
        pl16swap(b0, a0);
        pl16swap(b1, a1);
        pa[st][ks] = mk8(b0, b1, a0, a1);
      }
    }
    __builtin_amdgcn_s_setprio(1);
    #pragma unroll
    for (int ks = 0; ks < 2; ks++){
      Lacc[0] = __builtin_amdgcn_mfma_f32_16x16x32_bf16(ones, pa[0][ks], Lacc[0], 0, 0, 0);
      Lacc[1] = __builtin_amdgcn_mfma_f32_16x16x32_bf16(ones, pa[1][ks], Lacc[1], 0, 0, 0);
      #pragma unroll
      for (int df = 0; df < 4; df++){
        bf16x8 vf = *(const bf16x8*)(vbuf + (df * 16 + li) * 128 + (ks ? vp1 : vp0));
        O[0][df] = __builtin_amdgcn_mfma_f32_16x16x32_bf16(vf, pa[0][ks], O[0][df], 0, 0, 0);
        O[1][df] = __builtin_amdgcn_mfma_f32_16x16x32_bf16(vf, pa[1][ks], O[1][df], 0, 0, 0);
      }
    }
    __builtin_amdgcn_s_setprio(0);
  };

  char* B0 = SL[0]; char* B1 = SL[1]; char* B2 = SL[2];
  stage(0, B0);
  stage(1, B1);
  asm volatile("s_waitcnt vmcnt(4)" ::: "memory");
  __builtin_amdgcn_sched_barrier(0);
  __builtin_amdgcn_s_barrier();
  __builtin_amdgcn_sched_barrier(0);

  f32x4 sc[2][4], scN[2][4];
  qkt(B0, sc);

  for (int t = 0; t < 32; t++){
    asm volatile("s_waitcnt vmcnt(0)" ::: "memory");
    __builtin_amdgcn_sched_barrier(0);
    __builtin_amdgcn_s_barrier();
    __builtin_amdgcn_sched_barrier(0);

    if (t < 30) stage(t + 2, B2);
    if (t < 31) qkt(B1, scN);
    sfpv(sc, B0 + 8192);

    char* tmp = B0; B0 = B1; B1 = B2; B2 = tmp;
    #pragma unroll
    for (int s2 = 0; s2 < 2; s2++)
      #pragma unroll
      for (int fn = 0; fn < 4; fn++) sc[s2][fn] = scN[s2][fn];
  }

  const int rowb = b * 2048 + qt * 128 + wid * 32;
  #pragma unroll
  for (int st = 0; st < 2; st++){
    const float inv = 1.0f / Lacc[st][0];
    #pragma unroll
    for (int df = 0; df < 4; df++){
      ushort4 hv;
      #pragma unroll
      for (int r = 0; r < 4; r++)
        ((u16*)&hv)[r] = f2bf(O[st][df][r] * inv);
      size_t idx = (size_t)(rowb + st * 16 + li) * 1024 + h * 64 + df * 16 + g * 4;
      *(ushort4*)(AOh + idx) = hv;
    }
  }
}

// ---------------------------------------------------------------- launch
extern "C" void kernel_launch(void* const* d_in, const int* in_sizes, int n_in,
                              void* d_out, int out_size, void* d_ws, size_t ws_size,
                              hipStream_t stream)
{
  (void)in_sizes; (void)n_in; (void)out_size; (void)ws_size;
  const float* query = (const float*)d_in[0];
  const float* key_  = (const float*)d_in[1];
  const float* value = (const float*)d_in[2];
  const float* W1 = (const float*)d_in[3];
  const float* b1 = (const float*)d_in[4];
  const float* W2 = (const float*)d_in[5];
  const float* b2 = (const float*)d_in[6];
  const float* W3 = (const float*)d_in[7];
  const float* b3 = (const float*)d_in[8];
  const float* W4 = (const float*)d_in[9];
  const float* b4 = (const float*)d_in[10];

  char* w = (char*)d_ws;
  const size_t MB = (size_t)1 << 20;
  u16* w1h = (u16*)(w + 24 * MB);
  u16* w2h = (u16*)(w + 26 * MB);
  u16* w3h = (u16*)(w + 28 * MB);
  u16* w4h = (u16*)(w + 30 * MB);
  u16* Qb  = (u16*)(w + 32 * MB);
  u16* Kb  = (u16*)(w + 40 * MB);
  u16* VbT = (u16*)(w + 56 * MB);
  u16* AOh = (u16*)(w + 64 * MB);

  conv_all<<<4096, 256, 0, stream>>>(W1, W2, W3, W4, w1h, w2h, w3h, w4h);

  proj_kernel<<<768, 256, 0, stream>>>(query, key_, value, w1h, w2h, w3h,
                                       b1, b2, b3, Qb, Kb, VbT);
  attn_kernel<<<512, 256, 0, stream>>>(Qb, Kb, VbT, AOh);
  fin_kernel<<<512, 256, 0, stream>>>(AOh, w4h, b4, (float*)d_out);
}

// Round 21
// 111.303 us; speedup vs baseline: 1.1632x; 1.1632x over previous
//
#include <hip/hip_runtime.h>
#include <hip/hip_bf16.h>
#include <stdint.h>

typedef unsigned short u16;
typedef unsigned int   u32;
typedef __attribute__((ext_vector_type(4))) float f32x4;
typedef __attribute__((ext_vector_type(8))) short bf16x8;

__device__ __forceinline__ u16 f2bf(float x){
  u32 u = __float_as_uint(x);
  return (u16)((u + 0x7fffu + ((u >> 16) & 1u)) >> 16);   // RNE
}

__device__ __forceinline__ u32 pkbf(float a, float b){
  __hip_bfloat162 t = __float22bfloat162_rn(make_float2(a, b));  // v_cvt_pk_bf16_f32
  u32 r; __builtin_memcpy(&r, &t, 4); return r;
}

// raw v_exp_f32 (2^x): args always in [-50,-17] -> OCML range-fixup is dead code.
__device__ __forceinline__ float fexp2(float x){
  float r; asm("v_exp_f32 %0, %1" : "=v"(r) : "v"(x)); return r;
}

// v_permlane16_swap_b32 (Sem A, HW-confirmed R6/R7): d.row1<->s.row0, d.row3<->s.row2.
__device__ __forceinline__ void pl16swap(u32 &d, u32 &s){
  asm("v_permlane16_swap_b32 %0, %1" : "+v"(d), "+v"(s));
}

__device__ __forceinline__ bf16x8 mk8(u32 a, u32 b, u32 c, u32 d){
  union { u32 w[4]; bf16x8 v; } t; t.w[0]=a; t.w[1]=b; t.w[2]=c; t.w[3]=d; return t.v;
}

__device__ __forceinline__ void async_cp16(const void* g, void* l){
  __builtin_amdgcn_global_load_lds((const __attribute__((address_space(1))) void*)g,
                                   (__attribute__((address_space(3))) void*)l, 16, 0, 0);
}

// ---------------------------------------------------------------- converts: WEIGHTS ONLY
__device__ __forceinline__ void conv_body(const float* __restrict__ x,
                                          u16* __restrict__ hi, int i){
  float4 v = *(const float4*)(x + i);
  ushort4 hv; hv.x = f2bf(v.x); hv.y = f2bf(v.y); hv.z = f2bf(v.z); hv.w = f2bf(v.w);
  *(ushort4*)(hi + i) = hv;
}

__global__ __launch_bounds__(256) void conv_all(
    const float* __restrict__ w1, const float* __restrict__ w2,
    const float* __restrict__ w3, const float* __restrict__ w4,
    u16* w1h, u16* w2h, u16* w3h, u16* w4h)
{
  const int o = blockIdx.x;
  const int z = o >> 10;
  const int blk = o & 1023;
  const float* x = (z == 0) ? w1 : (z == 1) ? w2 : (z == 2) ? w3 : w4;
  u16* y = (z == 0) ? w1h : (z == 1) ? w2h : (z == 2) ? w3h : w4h;
  conv_body(x, y, (blk * 256 + threadIdx.x) * 4);
}

// ---------------------------------------------------------------- fused proj (R19 revert)
// Two-barrier pipeline, single lA (written between barriers), double lB, 48KB LDS,
// __launch_bounds__(256,3). Measured best (R19: total 112.0 us).
__global__ __launch_bounds__(256, 3) void proj_kernel(
    const float* __restrict__ qf, const float* __restrict__ kf, const float* __restrict__ vf,
    const u16* __restrict__ w1h, const u16* __restrict__ w2h, const u16* __restrict__ w3h,
    const float* b1, const float* b2, const float* b3,
    u16* Qb, u16* Kb, u16* VbT)
{
  __shared__ u16 lA[8192];
  __shared__ u16 lB[2][8192];

  const int o = blockIdx.x;
  const int swz = (o & 7) * 96 + (o >> 3);
  const int x = swz & 7, y = (swz >> 3) & 31, z = swz >> 8;
  const float* Af; const u16* Bw; const float* bs; float sc;
  if (z == 0){ Af = qf; Bw = w1h; bs = b1; sc = 0.18033688011112042f; }   // 1/sqrt(dk) * log2e
  else if (z == 1){ Af = kf; Bw = w2h; bs = b2; sc = 1.0f; }
  else { Af = vf; Bw = w3h; bs = b3; sc = 1.0f; }

  const int tid  = threadIdx.x;
  const int lane = tid & 63, wid = tid >> 6;
  const int li = lane & 15, g = lane >> 4;
  const int wr = wid >> 1, wc = wid & 1;
  const int m0 = y * 128, n0 = x * 128;

  const int r0 = tid >> 3, c0 = tid & 7;
  const size_t gsB = (size_t)r0 * 1024 + (size_t)((c0 ^ (r0 & 7)) * 8);
  const u16* pB = Bw + (size_t)n0 * 1024;

  const int ar0 = wid * 32 + (lane >> 3);
  const int ac  = lane & 7;
  const int awb = ((ac ^ (lane >> 3)) << 4);
  const float* pA = Af + (size_t)m0 * 1024;

  float4 ap[4][2];
  auto loadA = [&](int k0){
    #pragma unroll
    for (int p = 0; p < 4; p++){
      const float* s = pA + (size_t)(ar0 + 8 * p) * 1024 + k0 + ac * 8;
      ap[p][0] = *(const float4*)s;
      ap[p][1] = *(const float4*)(s + 4);
    }
  };

  f32x4 acc[4][4];
  #pragma unroll
  for (int i = 0; i < 4; i++)
    #pragma unroll
    for (int j = 0; j < 4; j++) acc[i][j] = (f32x4){0.f, 0.f, 0.f, 0.f};

  loadA(0);
  #pragma unroll
  for (int s = 0; s < 4; s++)
    async_cp16(pB + gsB + (size_t)s * 32 * 1024, (char*)lB + wid * 1024 + s * 4096);

  int cur = 0;
  for (int t = 0; t < 16; t++){
    const int k0 = t * 64;
    __builtin_amdgcn_s_barrier();
    asm volatile("s_waitcnt vmcnt(0)" ::: "memory");
    __builtin_amdgcn_sched_barrier(0);

    #pragma unroll
    for (int p = 0; p < 4; p++){
      uint4 wv;
      wv.x = pkbf(ap[p][0].x, ap[p][0].y);
      wv.y = pkbf(ap[p][0].z, ap[p][0].w);
      wv.z = pkbf(ap[p][1].x, ap[p][1].y);
      wv.w = pkbf(ap[p][1].z, ap[p][1].w);
      *(uint4*)((char*)lA + (ar0 + 8 * p) * 128 + awb) = wv;
    }
    if (t < 15){
      loadA(k0 + 64);
      #pragma unroll
      for (int s = 0; s < 4; s++)
        async_cp16(pB + gsB + (k0 + 64) + (size_t)s * 32 * 1024,
                   (char*)lB + (cur ^ 1) * 16384 + wid * 1024 + s * 4096);
    }
    asm volatile("s_waitcnt lgkmcnt(0)" ::: "memory");
    __builtin_amdgcn_sched_barrier(0);
    __builtin_amdgcn_s_barrier();

    const char* Bb = (const char*)lB + cur * 16384;
    #pragma unroll
    for (int kk = 0; kk < 2; kk++){
      bf16x8 af[4], bf4[4];
      #pragma unroll
      for (int f = 0; f < 4; f++){
        int ar = wr * 64 + f * 16 + li;
        int ja = (kk * 4 + g) ^ (ar & 7);
        af[f] = *(const bf16x8*)((const char*)lA + ar * 128 + (ja << 4));
        int br = wc * 64 + f * 16 + li;
        int jb = (kk * 4 + g) ^ (br & 7);
        bf4[f] = *(const bf16x8*)(Bb + br * 128 + (jb << 4));
      }
      __builtin_amdgcn_s_setprio(1);
      #pragma unroll
      for (int fm = 0; fm < 4; fm++)
        #pragma unroll
        for (int fn = 0; fn < 4; fn++)
          acc[fm][fn] = __builtin_amdgcn_mfma_f32_16x16x32_bf16(af[fm], bf4[fn], acc[fm][fn], 0, 0, 0);
      __builtin_amdgcn_s_setprio(0);
    }
    cur ^= 1;
  }

  float bv[4];
  #pragma unroll
  for (int fn = 0; fn < 4; fn++) bv[fn] = bs[n0 + wc * 64 + fn * 16 + li];

  if (z != 2){
    u16* out = (z == 0) ? Qb : Kb;
    #pragma unroll
    for (int fm = 0; fm < 4; fm++){
      const int mb = m0 + wr * 64 + fm * 16 + g * 4;
      #pragma unroll
      for (int fn = 0; fn < 4; fn++){
        const int n = n0 + wc * 64 + fn * 16 + li;
        #pragma unroll
        for (int r = 0; r < 4; r++)
          out[(size_t)(mb + r) * 1024 + n] = f2bf((acc[fm][fn][r] + bv[fn]) * sc);
      }
    }
  } else {
    // transposed: VbT[((b*16+h)*64+d)*2048 + seq], seq = (m0&2047)+wr*64+fm*16+g*4+r
    const int bb = m0 >> 11;
    const int sq0 = (m0 & 2047) + wr * 64 + g * 4;
    #pragma unroll
    for (int fm = 0; fm < 4; fm++){
      #pragma unroll
      for (int fn = 0; fn < 4; fn++){
        const int n = n0 + wc * 64 + fn * 16 + li;
        const int hh = n >> 6, dd = n & 63;
        ushort4 hv;
        #pragma unroll
        for (int r = 0; r < 4; r++)
          ((u16*)&hv)[r] = f2bf(acc[fm][fn][r] + bv[fn]);
        size_t idx = ((size_t)(bb * 16 + hh) * 64 + dd) * 2048 + sq0 + fm * 16;
        *(ushort4*)(VbT + idx) = hv;
      }
    }
  }
}

// ---------------------------------------------------------------- fin: 128x64 tile, 512 blocks (2/CU)
__global__ __launch_bounds__(256, 2) void fin_kernel(
    const u16* __restrict__ A, const u16* __restrict__ B,
    const float* __restrict__ bias, float* __restrict__ out)
{
  __shared__ u16 lA[8192], lB[4096];   // A 128x64 (16KB), B 64x64 (8KB)
  const int tid  = threadIdx.x;
  const int lane = tid & 63, wid = tid >> 6;
  const int li = lane & 15, g = lane >> 4;
  const int wr = wid >> 1, wc = wid & 1;

  const int o = blockIdx.x;
  const int swz = (o & 7) * 64 + (o >> 3);
  const int x = swz & 15, y = swz >> 4;
  const int m0 = y * 128, n0 = x * 64;

  const u16* pA = A + (size_t)m0 * 1024;
  const u16* pB = B + (size_t)n0 * 1024;

  const int r0 = tid >> 3, c0 = tid & 7;
  const size_t gsrc = (size_t)r0 * 1024 + (size_t)((c0 ^ (r0 & 7)) * 8);
  char* dA = (char*)lA + wid * 1024;
  char* dB = (char*)lB + wid * 1024;

  f32x4 acc[4][2];
  #pragma unroll
  for (int i = 0; i < 4; i++)
    #pragma unroll
    for (int j = 0; j < 2; j++) acc[i][j] = (f32x4){0.f, 0.f, 0.f, 0.f};

  for (int k0 = 0; k0 < 1024; k0 += 64){
    __syncthreads();
    #pragma unroll
    for (int s = 0; s < 4; s++)
      async_cp16(pA + gsrc + k0 + (size_t)s * 32 * 1024, dA + s * 4096);
    #pragma unroll
    for (int s = 0; s < 2; s++)
      async_cp16(pB + gsrc + k0 + (size_t)s * 32 * 1024, dB + s * 4096);
    __syncthreads();

    #pragma unroll
    for (int kk = 0; kk < 2; kk++){
      bf16x8 af[4], bf2[2];
      #pragma unroll
      for (int f = 0; f < 4; f++){
        int ar = wr * 64 + f * 16 + li;
        int ja = (kk * 4 + g) ^ (ar & 7);
        af[f] = *(const bf16x8*)((const char*)lA + ar * 128 + (ja << 4));
      }
      #pragma unroll
      for (int f = 0; f < 2; f++){
        int br = wc * 32 + f * 16 + li;
        int jb = (kk * 4 + g) ^ (br & 7);
        bf2[f] = *(const bf16x8*)((const char*)lB + br * 128 + (jb << 4));
      }
      __builtin_amdgcn_s_setprio(1);
      #pragma unroll
      for (int fm = 0; fm < 4; fm++)
        #pragma unroll
        for (int fn = 0; fn < 2; fn++)
          acc[fm][fn] = __builtin_amdgcn_mfma_f32_16x16x32_bf16(af[fm], bf2[fn], acc[fm][fn], 0, 0, 0);
      __builtin_amdgcn_s_setprio(0);
    }
  }

  float bv[2];
  #pragma unroll
  for (int fn = 0; fn < 2; fn++) bv[fn] = bias[n0 + wc * 32 + fn * 16 + li];

  #pragma unroll
  for (int fm = 0; fm < 4; fm++){
    const int mb = m0 + wr * 64 + fm * 16 + g * 4;
    #pragma unroll
    for (int fn = 0; fn < 2; fn++){
      const int n = n0 + wc * 32 + fn * 16 + li;
      #pragma unroll
      for (int r = 0; r < 4; r++)
        out[(size_t)(mb + r) * 1024 + n] = acc[fm][fn][r] + bv[fn];
    }
  }
}

// ---------------------------------------------------------------- flash attention v13 (frozen)
__global__ __launch_bounds__(256) void attn_kernel(
    const u16* __restrict__ Qb, const u16* __restrict__ Kb, const u16* __restrict__ VbT,
    u16* __restrict__ AOh)
{
  __shared__ char SL[3][16384];   // per buf: K [64k][64d] 8KB, V [64d][64k] 8KB

  const int tid = threadIdx.x;
  const int lane = tid & 63, wid = tid >> 6;
  const int li = lane & 15, g = lane >> 4;

  const int o = blockIdx.x;
  const int swz = (o & 7) * 64 + (o >> 3);
  const int qt = swz & 15, h = (swz >> 4) & 15, b = swz >> 8;

  const int r0 = tid >> 3, ch = tid & 7;
  const int csw = (ch ^ (r0 & 7)) * 8;
  const u16* gK = Kb  + (size_t)(b * 2048 + r0) * 1024 + h * 64 + csw;
  const u16* gV = VbT + ((size_t)(b * 16 + h) * 64 + r0) * 2048 + csw;
  const int ldsW = wid * 1024;

  const int kb0 = li * 128 + ((g ^ (li & 7)) << 4);
  const int cm = ((((g & 1) << 1) | ((g >> 1) & 1)) ^ 2);
  const int vp0 = ((cm ^ (li & 7)) << 4);
  const int vp1 = (((4 + cm) ^ (li & 7)) << 4);

  const u16* qp = Qb + (size_t)(b * 2048 + qt * 128 + wid * 32 + li) * 1024 + h * 64 + g * 8;
  bf16x8 qf[2][2];
  qf[0][0] = *(const bf16x8*)(qp);
  qf[0][1] = *(const bf16x8*)(qp + 32);
  qf[1][0] = *(const bf16x8*)(qp + 16 * 1024);
  qf[1][1] = *(const bf16x8*)(qp + 16 * 1024 + 32);

  f32x4 O[2][4];
  #pragma unroll
  for (int st = 0; st < 2; st++)
    #pragma unroll
    for (int df = 0; df < 4; df++) O[st][df] = (f32x4){0.f, 0.f, 0.f, 0.f};
  f32x4 Lacc[2];
  Lacc[0] = (f32x4){0.f, 0.f, 0.f, 0.f};
  Lacc[1] = (f32x4){0.f, 0.f, 0.f, 0.f};
  const f32x4 NEGC = (f32x4){-32.f, -32.f, -32.f, -32.f};
  const u32 one2 = 0x3f803f80u;
  const bf16x8 ones = mk8(one2, one2, one2, one2);

  auto stage = [&](int t, char* buf){
    #pragma unroll
    for (int c = 0; c < 2; c++){
      async_cp16(gK + (size_t)(t * 64 + c * 32) * 1024, buf + c * 4096 + ldsW);
      async_cp16(gV + (size_t)c * 32 * 2048 + t * 64,   buf + 8192 + c * 4096 + ldsW);
    }
  };

  auto qkt = [&](const char* buf, f32x4 sc[2][4]){
    __builtin_amdgcn_s_setprio(1);
    #pragma unroll
    for (int fn = 0; fn < 4; fn++){
      bf16x8 kf0 = *(const bf16x8*)(buf + fn * 2048 + kb0);
      bf16x8 kf1 = *(const bf16x8*)(buf + fn * 2048 + (kb0 ^ 64));
      #pragma unroll
      for (int st = 0; st < 2; st++){
        f32x4 z = __builtin_amdgcn_mfma_f32_16x16x32_bf16(kf0, qf[st][0], NEGC, 0, 0, 0);
        sc[st][fn] = __builtin_amdgcn_mfma_f32_16x16x32_bf16(kf1, qf[st][1], z, 0, 0, 0);
      }
    }
    __builtin_amdgcn_s_setprio(0);
  };

  auto sfpv = [&](const f32x4 sc[2][4], const char* vbuf){
    bf16x8 pa[2][2];
    #pragma unroll
    for (int st = 0; st < 2; st++){
      float p[4][4];
      #pragma unroll
      for (int fn = 0; fn < 4; fn++)
        #pragma unroll
        for (int r = 0; r < 4; r++)
          p[fn][r] = fexp2(sc[st][fn][r]);
      #pragma unroll
      for (int ks = 0; ks < 2; ks++){
        u32 a0 = pkbf(p[2 * ks][0],     p[2 * ks][1]);
        u32 a1 = pkbf(p[2 * ks][2],     p[2 * ks][3]);
        u32 b0 = pkbf(p[2 * ks + 1][0], p[2 * ks + 1][1]);
        u32 b1 = pkbf(p[2 * ks + 1][2], p[2 * ks + 1][3]);
        pl16swap(b0, a0);
        pl16swap(b1, a1);
        pa[st][ks] = mk8(b0, b1, a0, a1);
      }
    }
    __builtin_amdgcn_s_setprio(1);
    #pragma unroll
    for (int ks = 0; ks < 2; ks++){
      Lacc[0] = __builtin_amdgcn_mfma_f32_16x16x32_bf16(ones, pa[0][ks], Lacc[0], 0, 0, 0);
      Lacc[1] = __builtin_amdgcn_mfma_f32_16x16x32_bf16(ones, pa[1][ks], Lacc[1], 0, 0, 0);
      #pragma unroll
      for (int df = 0; df < 4; df++){
        bf16x8 vf = *(const bf16x8*)(vbuf + (df * 16 + li) * 128 + (ks ? vp1 : vp0));
        O[0][df] = __builtin_amdgcn_mfma_f32_16x16x32_bf16(vf, pa[0][ks], O[0][df], 0, 0, 0);
        O[1][df] = __builtin_amdgcn_mfma_f32_16x16x32_bf16(vf, pa[1][ks], O[1][df], 0, 0, 0);
      }
    }
    __builtin_amdgcn_s_setprio(0);
  };

  char* B0 = SL[0]; char* B1 = SL[1]; char* B2 = SL[2];
  stage(0, B0);
  stage(1, B1);
  asm volatile("s_waitcnt vmcnt(4)" ::: "memory");
  __builtin_amdgcn_sched_barrier(0);
  __builtin_amdgcn_s_barrier();
  __builtin_amdgcn_sched_barrier(0);

  f32x4 sc[2][4], scN[2][4];
  qkt(B0, sc);

  for (int t = 0; t < 32; t++){
    asm volatile("s_waitcnt vmcnt(0)" ::: "memory");
    __builtin_amdgcn_sched_barrier(0);
    __builtin_amdgcn_s_barrier();
    __builtin_amdgcn_sched_barrier(0);

    if (t < 30) stage(t + 2, B2);
    if (t < 31) qkt(B1, scN);
    sfpv(sc, B0 + 8192);

    char* tmp = B0; B0 = B1; B1 = B2; B2 = tmp;
    #pragma unroll
    for (int s2 = 0; s2 < 2; s2++)
      #pragma unroll
      for (int fn = 0; fn < 4; fn++) sc[s2][fn] = scN[s2][fn];
  }

  const int rowb = b * 2048 + qt * 128 + wid * 32;
  #pragma unroll
  for (int st = 0; st < 2; st++){
    const float inv = 1.0f / Lacc[st][0];
    #pragma unroll
    for (int df = 0; df < 4; df++){
      ushort4 hv;
      #pragma unroll
      for (int r = 0; r < 4; r++)
        ((u16*)&hv)[r] = f2bf(O[st][df][r] * inv);
      size_t idx = (size_t)(rowb + st * 16 + li) * 1024 + h * 64 + df * 16 + g * 4;
      *(ushort4*)(AOh + idx) = hv;
    }
  }
}

// ---------------------------------------------------------------- launch
extern "C" void kernel_launch(void* const* d_in, const int* in_sizes, int n_in,
                              void* d_out, int out_size, void* d_ws, size_t ws_size,
                              hipStream_t stream)
{
  (void)in_sizes; (void)n_in; (void)out_size; (void)ws_size;
  const float* query = (const float*)d_in[0];
  const float* key_  = (const float*)d_in[1];
  const float* value = (const float*)d_in[2];
  const float* W1 = (const float*)d_in[3];
  const float* b1 = (const float*)d_in[4];
  const float* W2 = (const float*)d_in[5];
  const float* b2 = (const float*)d_in[6];
  const float* W3 = (const float*)d_in[7];
  const float* b3 = (const float*)d_in[8];
  const float* W4 = (const float*)d_in[9];
  const float* b4 = (const float*)d_in[10];

  char* w = (char*)d_ws;
  const size_t MB = (size_t)1 << 20;
  u16* w1h = (u16*)(w + 24 * MB);
  u16* w2h = (u16*)(w + 26 * MB);
  u16* w3h = (u16*)(w + 28 * MB);
  u16* w4h = (u16*)(w + 30 * MB);
  u16* Qb  = (u16*)(w + 32 * MB);
  u16* Kb  = (u16*)(w + 40 * MB);
  u16* VbT = (u16*)(w + 56 * MB);
  u16* AOh = (u16*)(w + 64 * MB);

  conv_all<<<4096, 256, 0, stream>>>(W1, W2, W3, W4, w1h, w2h, w3h, w4h);

  proj_kernel<<<768, 256, 0, stream>>>(query, key_, value, w1h, w2h, w3h,
                                       b1, b2, b3, Qb, Kb, VbT);
  attn_kernel<<<512, 256, 0, stream>>>(Qb, Kb, VbT, AOh);
  fin_kernel<<<512, 256, 0, stream>>>(AOh, w4h, b4, (float*)d_out);
}